// Round 3
// baseline (52.632 us; speedup 1.0000x reference)
//
#include <hip/hip_runtime.h>

// LowFreqPenaltyLoss: mean(|truncated 2-D DCT (8x8) of each 256x256 image|)
// delta: [256,3,256,256] f32 -> scalar f32.
// Basis C[k,n] = 2*cos(pi*(2n+1)*k/512), identical for H and W.
// Per image: u[w][i] = sum_h C[i,h]*X[h,w]; low[i,j] = sum_w C[j,w]*u[w][i].
//
// R3 structure: 512-thread blocks (8 waves x 32 rows), epilogue through a
// shared u-slab instead of per-thread v[64] -> VGPR ~70, 3 blocks/CU
// resident = 24 waves/CU (was 12). __launch_bounds__(512,6) caps VGPR at 85.

#define INV_COUNT (1.0f / 49152.0f)  // 256*3*8*8

__global__ __launch_bounds__(512, 6) void lowfreq_main(
    const float* __restrict__ delta, float* __restrict__ out)
{
    __shared__ float c_row[256][8];   // basis, broadcast-read by row h (8 KB)
    __shared__ float c_col[8][260];   // basis transposed, pad->bank spread (8.1 KB)
    __shared__ float u_lds[8][260];   // u[i][w] summed over all 8 waves (8.1 KB)
    __shared__ float pacc[8][64];     // per-wave partial low slots (2 KB)

    const int t = threadIdx.x;
    const int wave = t >> 6;
    const int lane = t & 63;

    // Phase 0: DCT-II basis (unnormalized, torch_dct norm=None convention)
    if (t < 256) {
        const float base = 3.14159265358979323846f * (2.0f * (float)t + 1.0f)
                           * (1.0f / 512.0f);
        #pragma unroll
        for (int k = 0; k < 8; ++k) {
            const float v = 2.0f * cosf(base * (float)k);
            c_row[t][k] = v;
            c_col[k][t] = v;
        }
    }
    __syncthreads();

    // Phase 1: wave w streams rows [32w, 32w+32). Thread owns 4 consecutive
    // columns {4*lane..4*lane+3} -> one float4 per row, wave covers the
    // 1024B row in one dwordx4.
    const float* img = delta + (size_t)blockIdx.x * 65536;
    const float4* gp = reinterpret_cast<const float4*>(img) + (wave << 11) + lane;

    float u[4][8];
    #pragma unroll
    for (int c = 0; c < 4; ++c)
        #pragma unroll
        for (int i = 0; i < 8; ++i) u[c][i] = 0.0f;

    #pragma unroll 4
    for (int r = 0; r < 32; ++r) {
        const int h = (wave << 5) + r;
        const float4 x = gp[r << 6];
        const float4 cA = *reinterpret_cast<const float4*>(&c_row[h][0]);
        const float4 cB = *reinterpret_cast<const float4*>(&c_row[h][4]);
        const float cc[8] = {cA.x, cA.y, cA.z, cA.w, cB.x, cB.y, cB.z, cB.w};
        #pragma unroll
        for (int i = 0; i < 8; ++i) {
            u[0][i] = fmaf(cc[i], x.x, u[0][i]);
            u[1][i] = fmaf(cc[i], x.y, u[1][i]);
            u[2][i] = fmaf(cc[i], x.z, u[2][i]);
            u[3][i] = fmaf(cc[i], x.w, u[3][i]);
        }
    }

    // Phase 2: staged cross-wave accumulation into u_lds[i][w].
    // Thread's 4 columns are contiguous -> float4 RMW, lane l touches bytes
    // [16l,16l+16) of each row: dense, conflict-free. Stage 0 writes (no init).
    #pragma unroll 1
    for (int s = 0; s < 8; ++s) {
        if (wave == s) {
            #pragma unroll
            for (int i = 0; i < 8; ++i) {
                float4* p = reinterpret_cast<float4*>(&u_lds[i][lane << 2]);
                float4 acc;
                if (s == 0) acc = make_float4(0.f, 0.f, 0.f, 0.f);
                else        acc = *p;
                acc.x += u[0][i]; acc.y += u[1][i];
                acc.z += u[2][i]; acc.w += u[3][i];
                *p = acc;
            }
        }
        __syncthreads();
    }

    // Phase 3: lane owns slot (i,j) = (lane>>3, lane&7); wave contracts its
    // 32-column range w in [32*wave, 32*wave+32). float4 reads: 8 distinct
    // 16B addresses per instr (broadcast over j) covering all 32 banks.
    {
        const int i = lane >> 3;
        const int j = lane & 7;
        const int w0 = wave << 5;
        const float4* up = reinterpret_cast<const float4*>(&u_lds[i][w0]);
        const float4* cp = reinterpret_cast<const float4*>(&c_col[j][w0]);
        float s = 0.0f;
        #pragma unroll
        for (int k = 0; k < 8; ++k) {
            const float4 uv = up[k];
            const float4 cv = cp[k];
            s = fmaf(uv.x, cv.x, s);
            s = fmaf(uv.y, cv.y, s);
            s = fmaf(uv.z, cv.z, s);
            s = fmaf(uv.w, cv.w, s);
        }
        pacc[wave][lane] = s;
    }
    __syncthreads();

    // Phase 4: combine 8 waves per slot, abs, block sum, one atomic.
    if (t < 64) {
        float tot = pacc[0][t];
        #pragma unroll
        for (int k = 1; k < 8; ++k) tot += pacc[k][t];
        float a = fabsf(tot);
        #pragma unroll
        for (int m = 1; m < 64; m <<= 1) a += __shfl_xor(a, m, 64);
        if (t == 0) atomicAdd(out, a * INV_COUNT);
    }
}

extern "C" void kernel_launch(void* const* d_in, const int* in_sizes, int n_in,
                              void* d_out, int out_size, void* d_ws, size_t ws_size,
                              hipStream_t stream)
{
    const float* delta = (const float*)d_in[0];
    float* out = (float*)d_out;
    hipMemsetAsync(out, 0, sizeof(float) * (size_t)out_size, stream);
    lowfreq_main<<<768, 512, 0, stream>>>(delta, out);
}

// Round 4
// 40.484 us; speedup vs baseline: 1.3001x; 1.3001x over previous
//
#include <hip/hip_runtime.h>

// LowFreqPenaltyLoss: mean(|truncated 2-D DCT (8x8) of each 256x256 image|)
// delta: [256,3,256,256] f32 -> scalar f32.
// Basis C[k,n] = 2*cos(pi*(2n+1)*k/512), identical for H and W.
// Per image: u[w][i] = sum_h C[i,h]*X[h,w]; low[i,j] = sum_w C[j,w]*u[w][i].
//
// R4: 1536 blocks (half-image each: finer granularity -> load balance),
// pre-abs partials to ws, tiny pair+abs+sum reduce kernel, no memset
// dispatch (block 0 zeroes out), Chebyshev basis (1 cosf not 8).

#define INV_COUNT (1.0f / 49152.0f)  // 256*3*8*8

__global__ __launch_bounds__(256, 3) void lowfreq_main(
    const float* __restrict__ delta, float* __restrict__ ws,
    float* __restrict__ out)
{
    __shared__ float c_row[256][8];  // basis, wave-uniform broadcast by row h
    __shared__ float c_col[8][256];  // transposed, per-lane epilogue reads
    __shared__ float pacc[4][64];

    const int t = threadIdx.x;
    const int wave = t >> 6;
    const int lane = t & 63;
    const int bid = blockIdx.x;
    const int img = bid >> 1;        // (n,c) image index
    const int half = bid & 1;        // rows [0,128) or [128,256)

    // Phase 0: DCT-II basis row t via Chebyshev recurrence:
    // cos((k+1)a) = 2cos(a)cos(ka) - cos((k-1)a); store 2*cos(ka).
    {
        const float a = 3.14159265358979323846f * (2.0f * (float)t + 1.0f)
                        * (1.0f / 512.0f);
        const float ca = cosf(a);
        float ckm1 = 1.0f;   // cos(0)
        float ck   = ca;     // cos(a)
        c_row[t][0] = 2.0f;  c_col[0][t] = 2.0f;
        c_row[t][1] = 2.0f * ca;  c_col[1][t] = 2.0f * ca;
        #pragma unroll
        for (int k = 2; k < 8; ++k) {
            const float cn = 2.0f * ca * ck - ckm1;
            ckm1 = ck; ck = cn;
            c_row[t][k] = 2.0f * cn;
            c_col[k][t] = 2.0f * cn;
        }
    }
    __syncthreads();

    // Phase 1: this block streams rows [half*128, half*128+128); wave w owns
    // 32 of them. Thread owns columns {lane, lane+64, lane+128, lane+192}
    // (dword loads, stride 64 — the R0 pattern that benched fastest).
    const int row0 = (half << 7) + (wave << 5);
    const float* gp = delta + (size_t)img * 65536 + (size_t)row0 * 256 + lane;

    float u[4][8];
    #pragma unroll
    for (int c = 0; c < 4; ++c)
        #pragma unroll
        for (int i = 0; i < 8; ++i) u[c][i] = 0.0f;

    #pragma unroll 4
    for (int r = 0; r < 32; ++r) {
        const int h = row0 + r;
        const float x0 = gp[r * 256 + 0];
        const float x1 = gp[r * 256 + 64];
        const float x2 = gp[r * 256 + 128];
        const float x3 = gp[r * 256 + 192];
        const float4 cA = *reinterpret_cast<const float4*>(&c_row[h][0]);
        const float4 cB = *reinterpret_cast<const float4*>(&c_row[h][4]);
        const float cc[8] = {cA.x, cA.y, cA.z, cA.w, cB.x, cB.y, cB.z, cB.w};
        #pragma unroll
        for (int i = 0; i < 8; ++i) {
            u[0][i] = fmaf(cc[i], x0, u[0][i]);
            u[1][i] = fmaf(cc[i], x1, u[1][i]);
            u[2][i] = fmaf(cc[i], x2, u[2][i]);
            u[3][i] = fmaf(cc[i], x3, u[3][i]);
        }
    }

    // Phase 2: per-thread partial low[i][j] over its 4 columns (w = c*64+lane).
    float cw[4][8];
    #pragma unroll
    for (int c = 0; c < 4; ++c)
        #pragma unroll
        for (int j = 0; j < 8; ++j)
            cw[c][j] = c_col[j][(c << 6) + lane];

    float v[64];
    #pragma unroll
    for (int i = 0; i < 8; ++i)
        #pragma unroll
        for (int j = 0; j < 8; ++j) {
            float s = u[0][i] * cw[0][j];
            s = fmaf(u[1][i], cw[1][j], s);
            s = fmaf(u[2][i], cw[2][j], s);
            s = fmaf(u[3][i], cw[3][j], s);
            v[(i << 3) + j] = s;
        }

    // Phase 3: slot-splitting butterfly — transpose+reduce 64 slots across the
    // wave; at the end lane l holds the wave total of slot l = (i<<3|j).
    #pragma unroll
    for (int s = 0; s < 6; ++s) {
        const int m = 1 << s;
        const bool bit = (lane & m) != 0;
        #pragma unroll
        for (int k = 0; k < (64 >> (s + 1)); ++k) {
            const float a = v[2 * k];
            const float b = v[2 * k + 1];
            const float keep = bit ? b : a;
            const float send = bit ? a : b;
            const float recv = __shfl_xor(send, m, 64);
            v[k] = keep + recv;
        }
    }

    pacc[wave][lane] = v[0];
    __syncthreads();

    // Phase 4: combine 4 waves; write PRE-ABS half-image partials to ws.
    if (t < 64) {
        const float s4 = pacc[0][t] + pacc[1][t] + pacc[2][t] + pacc[3][t];
        ws[(size_t)bid * 64 + t] = s4;
        if (bid == 0 && t == 0) out[0] = 0.0f;  // stream-ordered before reduce
    }
}

// Pair the two half-image partials, abs, sum all 49152 slots into out.
__global__ __launch_bounds__(256) void lowfreq_reduce(
    const float* __restrict__ ws, float* __restrict__ out)
{
    __shared__ float acc[4];
    const int t = threadIdx.x;
    const int wave = t >> 6;
    const int lane = t & 63;
    const int g = blockIdx.x * 256 + t;       // 192*256 = 49152 = 768*64
    const int img = g >> 6;
    const int slot = g & 63;

    const float s = ws[(size_t)(2 * img) * 64 + slot]
                  + ws[(size_t)(2 * img + 1) * 64 + slot];
    float a = fabsf(s);
    #pragma unroll
    for (int m = 1; m < 64; m <<= 1) a += __shfl_xor(a, m, 64);
    if (lane == 0) acc[wave] = a;
    __syncthreads();
    if (t == 0)
        atomicAdd(out, (acc[0] + acc[1] + acc[2] + acc[3]) * INV_COUNT);
}

extern "C" void kernel_launch(void* const* d_in, const int* in_sizes, int n_in,
                              void* d_out, int out_size, void* d_ws, size_t ws_size,
                              hipStream_t stream)
{
    const float* delta = (const float*)d_in[0];
    float* out = (float*)d_out;
    float* ws = (float*)d_ws;  // 1536*64*4 B = 393 KB
    lowfreq_main<<<1536, 256, 0, stream>>>(delta, ws, out);
    lowfreq_reduce<<<192, 256, 0, stream>>>(ws, out);
}